// Round 5
// baseline (267.456 us; speedup 1.0000x reference)
//
#include <hip/hip_runtime.h>
#include <hip/hip_bf16.h>
#include <stdint.h>

#define M_DIM 8192
#define N_DIM 4096
#define K_DIM 4096

#define NT 64              // K-tiles of BK=64

using f32x4  = __attribute__((ext_vector_type(4))) float;
using bf16x8 = __attribute__((ext_vector_type(8))) __bf16;

typedef const __attribute__((address_space(1))) void glb_void_t;
typedef __attribute__((address_space(3))) void lds_void_t;

__device__ __forceinline__ void async16(const void* g, void* l) {
    // direct global->LDS, 16B per lane (dest = wave-uniform base + lane*16)
    __builtin_amdgcn_global_load_lds((glb_void_t*)(uintptr_t)g,
                                     (lds_void_t*)(uint32_t)(uintptr_t)l,
                                     16, 0, 0);
}

__device__ __forceinline__ unsigned short f32_to_bf16_rne(float f) {
    union { float f; uint32_t u; } v; v.f = f;
    uint32_t u = v.u;
    u += 0x7FFFu + ((u >> 16) & 1u);
    return (unsigned short)(u >> 16);
}

__device__ __forceinline__ unsigned short sign_to_bf16(float f) {
    union { float f; uint32_t u; } v; v.f = f;
    if ((v.u & 0x7FFFFFFFu) == 0u) return 0;                      // sign(0) = 0
    return (unsigned short)(0x3F80u | ((v.u >> 16) & 0x8000u));   // +-1.0 bf16
}

// ---- Phase 1: conversions (memory-bound, 16B loads / 16B stores) ----

__global__ void convert_x_kernel(const float* __restrict__ x,
                                 unsigned short* __restrict__ xb, int n8) {
    int stride = gridDim.x * blockDim.x;
    for (int i = blockIdx.x * blockDim.x + threadIdx.x; i < n8; i += stride) {
        const float4* p = (const float4*)x + (size_t)i * 2;
        float4 a = p[0], b = p[1];
        uint4 o;
        o.x = (uint32_t)f32_to_bf16_rne(a.x) | ((uint32_t)f32_to_bf16_rne(a.y) << 16);
        o.y = (uint32_t)f32_to_bf16_rne(a.z) | ((uint32_t)f32_to_bf16_rne(a.w) << 16);
        o.z = (uint32_t)f32_to_bf16_rne(b.x) | ((uint32_t)f32_to_bf16_rne(b.y) << 16);
        o.w = (uint32_t)f32_to_bf16_rne(b.z) | ((uint32_t)f32_to_bf16_rne(b.w) << 16);
        ((uint4*)xb)[i] = o;
    }
}

__global__ void convert_w_kernel(const float* __restrict__ w,
                                 unsigned short* __restrict__ wb, int n8) {
    int stride = gridDim.x * blockDim.x;
    for (int i = blockIdx.x * blockDim.x + threadIdx.x; i < n8; i += stride) {
        const float4* p = (const float4*)w + (size_t)i * 2;
        float4 a = p[0], b = p[1];
        uint4 o;
        o.x = (uint32_t)sign_to_bf16(a.x) | ((uint32_t)sign_to_bf16(a.y) << 16);
        o.y = (uint32_t)sign_to_bf16(a.z) | ((uint32_t)sign_to_bf16(a.w) << 16);
        o.z = (uint32_t)sign_to_bf16(b.x) | ((uint32_t)sign_to_bf16(b.y) << 16);
        o.w = (uint32_t)sign_to_bf16(b.z) | ((uint32_t)sign_to_bf16(b.w) << 16);
        ((uint4*)wb)[i] = o;
    }
}

// ---- Phase 2: 256x256-tile GEMM, 16x16x32 MFMA, 2-barrier K-tile ----
// C = Xb (M x K) * Wb^T (K x N) + bias; Xb row-major MxK, Wb row-major NxK.
// LDS: [2 buf][4 sect: A0,A1,B0,B1][128 rows x 64 cols bf16] = 128 KiB.
// XOR-swizzle T2 (16x16-read conflict-free): colbyte ^= (row&7)<<4.
// Per K-tile: 4 phases (reads 8/8/4/4 b128, 16 MFMA each) but only TWO
// barriers (hazard ledger, round-5):
//   BAR_a after P2: last B-read (b k1, P2) retires at each wave's P2 lgkm0
//     before it arrives -> any wave past BAR_a may stage B(t+2) into buf.
//   BAR_b at tile end after vmcnt(4): per-wave drain (oldest 8 of 12 loads
//     landed = A(t+1),B(t+1)) happens-before other waves' next-tile reads;
//     also closes A-sect WAR (P3/P4 a-reads retired at P4 lgkm0).
// All other cross-phase windows are read-vs-read or disjoint sections.
// Waves decouple within a half-tile -> ds_reads overlap other waves' MFMA.

#define BAR   __builtin_amdgcn_s_barrier()
#define SCB0  __builtin_amdgcn_sched_barrier(0)
#define LGKM0 asm volatile("s_waitcnt lgkmcnt(0)" ::: "memory")
#define VM4   asm volatile("s_waitcnt vmcnt(4)" ::: "memory")
#define VM0   asm volatile("s_waitcnt vmcnt(0)" ::: "memory")

#define RDA(BUFV, MLO, KK) \
    _Pragma("unroll") for (int mm = 0; mm < 4; ++mm) \
        a[mm] = rdfrag((BUFV), wm, ((MLO) + mm) * 16, (KK));

#define RDB(BUFV, KK) \
    _Pragma("unroll") for (int nn = 0; nn < 4; ++nn) \
        b[nn][(KK)] = rdfrag((BUFV), sectB, rB + nn * 16, (KK));

#define MM16R(MB, KK) \
    __builtin_amdgcn_s_setprio(1); \
    _Pragma("unroll") for (int mm = 0; mm < 4; ++mm) \
    _Pragma("unroll") for (int nn = 0; nn < 4; ++nn) \
        acc[(MB) + mm][nn] = __builtin_amdgcn_mfma_f32_16x16x32_bf16( \
            a[mm], b[nn][(KK)], acc[(MB) + mm][nn], 0, 0, 0); \
    __builtin_amdgcn_s_setprio(0);

// One K-tile t. P1/P2 stage A-halves of t+1 (other buffer);
// P3/P4 stage B-halves of t+2 (current buffer, protected by BAR_a).
#define KT(T, SA, SB, VMW) do { \
    const int buf_ = (T) & 1; const int nbuf_ = buf_ ^ 1; \
    if (SA) stage(nbuf_, 0, xb, brow, ((T) + 1) * 64); \
    RDA(buf_, 0, 0) RDB(buf_, 0) \
    LGKM0; SCB0; \
    MM16R(0, 0) \
    if (SA) stage(nbuf_, 1, xb, brow + 128, ((T) + 1) * 64); \
    RDA(buf_, 0, 1) RDB(buf_, 1) \
    LGKM0; SCB0; \
    MM16R(0, 1) \
    BAR; SCB0;                       /* BAR_a: B-reads done -> B-stage safe */ \
    if (SB) stage(buf_, 2, wb, bcol, ((T) + 2) * 64); \
    RDA(buf_, 4, 0) \
    LGKM0; SCB0; \
    MM16R(4, 0) \
    if (SB) stage(buf_, 3, wb, bcol + 128, ((T) + 2) * 64); \
    RDA(buf_, 4, 1) \
    LGKM0; SCB0; \
    MM16R(4, 1) \
    VMW; \
    BAR; SCB0;                       /* BAR_b: staged data + A-sect WAR */ \
} while (0)

__global__ __launch_bounds__(512, 2)
void gemm_bin_kernel(const unsigned short* __restrict__ xb,
                     const unsigned short* __restrict__ wb,
                     const float* __restrict__ bias,
                     float* __restrict__ out) {
    __shared__ __align__(16) unsigned short lds[2][4][8192];

    const int tid  = threadIdx.x;
    const int wid  = tid >> 6;
    const int lane = tid & 63;

    // XCD-aware swizzle: 512 blocks, 8 XCDs, 64 contiguous tiles per XCD
    const int bid  = blockIdx.x;
    const int swzb = (bid & 7) * 64 + (bid >> 3);
    const int brow = (swzb >> 4) * 256;      // 32 M-tiles
    const int bcol = (swzb & 15) * 256;      // 16 N-tiles

    const int wm = wid >> 2;                 // 0..1: A half (row block of 128)
    const int wn = wid & 3;                  // 0..3: 64-col block
    const int fr  = lane & 15;
    const int g16 = (lane >> 4) << 4;        // k-group byte offset (16x16 frag)
    const int sw  = (lane & 7) << 4;         // T2 swizzle XOR == (row&7)<<4
    const int sectB = 2 + (wn >> 1);
    const int rB    = (wn & 1) * 64;

    f32x4  acc[8][4] = {};
    bf16x8 a[4], b[4][2];

    // staging: half-tile 128x64 bf16, 16 chunks of 1KB; wave w -> chunks 2w,2w+1.
    // linear LDS dest; global source pre-swizzled: colE = ((lane&7)^(lane>>3))*8
    const int ssub  = lane >> 3;
    const int scolE = ((lane & 7) ^ ssub) * 8;
    auto stage = [&](int bufv, int sect, const unsigned short* g, int row0, int k0) {
        unsigned short* lb = &lds[bufv][sect][0];
        #pragma unroll
        for (int j = 0; j < 2; ++j) {
            const int c = wid * 2 + j;
            const int r = c * 8 + ssub;
            async16(g + (size_t)(row0 + r) * K_DIM + (k0 + scolE),
                    lb + c * 512 + lane * 8);
        }
    };

    // 16x16 frag read: row = rbase + (lane&15), kbyte = kk*64 + (lane>>4)*16
    auto rdfrag = [&](int bufv, int sect, int rbase, int kk) -> bf16x8 {
        const char* base = (const char*)&lds[bufv][sect][0];
        const int off = (rbase + fr) * 128 + (((kk * 64) + g16) ^ sw);
        return *(const bf16x8*)(base + off);
    };

    // prologue: K-tile 0 (A0,A1,B0,B1 -> buf0) + B-halves of K-tile 1 -> buf1
    stage(0, 0, xb, brow,        0);
    stage(0, 1, xb, brow + 128,  0);
    stage(0, 2, wb, bcol,        0);
    stage(0, 3, wb, bcol + 128,  0);
    stage(1, 2, wb, bcol,       64);
    stage(1, 3, wb, bcol + 128, 64);
    VM4;                 // K-tile 0 fully landed; B(1) halves may be in flight
    BAR; SCB0;

    #pragma unroll 2
    for (int t = 0; t < NT - 2; ++t) KT(t, 1, 1, VM4);
    KT(NT - 2, 1, 0, VM0);           // stage A(63) only; drain before last tile
    KT(NT - 1, 0, 0, (void)0);       // pure compute

    // epilogue: C/D layout col = lane&15, row = (lane>>4)*4 + reg
    const int wrow = wm * 128, wcol = wn * 64;
    float bv[4];
    #pragma unroll
    for (int n = 0; n < 4; ++n) bv[n] = bias[bcol + wcol + n * 16 + fr];
    const int r4 = (lane >> 4) * 4;
    #pragma unroll
    for (int m = 0; m < 8; ++m) {
        #pragma unroll
        for (int rr = 0; rr < 4; ++rr) {
            const int row = brow + wrow + m * 16 + r4 + rr;
            float* orow = out + (size_t)row * N_DIM + bcol + wcol;
            #pragma unroll
            for (int n = 0; n < 4; ++n)
                orow[n * 16 + fr] = acc[m][n][rr] + bv[n];
        }
    }
}

// ---- Fallback if ws too small: naive fp32 (correct, slow; safety net) ----

__global__ void naive_kernel(const float* __restrict__ x,
                             const float* __restrict__ w,
                             const float* __restrict__ bias,
                             float* __restrict__ out) {
    const size_t total = (size_t)M_DIM * N_DIM;
    for (size_t idx = (size_t)blockIdx.x * blockDim.x + threadIdx.x; idx < total;
         idx += (size_t)gridDim.x * blockDim.x) {
        const size_t row = idx >> 12;
        const size_t col = idx & 4095;
        const float4* xr  = (const float4*)(x + row * K_DIM);
        const float4* wrp = (const float4*)(w + col * K_DIM);
        float s = 0.f;
        for (int k = 0; k < K_DIM / 4; ++k) {
            float4 a = xr[k], bq = wrp[k];
            s += a.x * (bq.x > 0.f ? 1.f : (bq.x < 0.f ? -1.f : 0.f));
            s += a.y * (bq.y > 0.f ? 1.f : (bq.y < 0.f ? -1.f : 0.f));
            s += a.z * (bq.z > 0.f ? 1.f : (bq.z < 0.f ? -1.f : 0.f));
            s += a.w * (bq.w > 0.f ? 1.f : (bq.w < 0.f ? -1.f : 0.f));
        }
        out[idx] = s + bias[col];
    }
}

extern "C" void kernel_launch(void* const* d_in, const int* in_sizes, int n_in,
                              void* d_out, int out_size, void* d_ws, size_t ws_size,
                              hipStream_t stream) {
    const float* x    = (const float*)d_in[0];
    const float* w    = (const float*)d_in[1];
    const float* bias = (const float*)d_in[2];
    float* out = (float*)d_out;

    const size_t xb_bytes = (size_t)M_DIM * K_DIM * 2;   // 64 MB
    const size_t wb_bytes = (size_t)N_DIM * K_DIM * 2;   // 32 MB

    if (ws_size >= xb_bytes + wb_bytes) {
        unsigned short* xb = (unsigned short*)d_ws;
        unsigned short* wb = (unsigned short*)((char*)d_ws + xb_bytes);
        convert_x_kernel<<<2048, 256, 0, stream>>>(x, xb, (int)((size_t)M_DIM * K_DIM / 8));
        convert_w_kernel<<<2048, 256, 0, stream>>>(w, wb, (int)((size_t)N_DIM * K_DIM / 8));
        gemm_bin_kernel<<<dim3((M_DIM / 256) * (N_DIM / 256)), dim3(512), 0, stream>>>(
            xb, wb, bias, out);
    } else {
        naive_kernel<<<4096, 256, 0, stream>>>(x, w, bias, out);
    }
}

// Round 6
// 262.102 us; speedup vs baseline: 1.0204x; 1.0204x over previous
//
#include <hip/hip_runtime.h>
#include <hip/hip_bf16.h>
#include <stdint.h>

#define M_DIM 8192
#define N_DIM 4096
#define K_DIM 4096

#define NT 64              // K-tiles of BK=64

using f32x4  = __attribute__((ext_vector_type(4))) float;
using bf16x8 = __attribute__((ext_vector_type(8))) __bf16;

typedef const __attribute__((address_space(1))) void glb_void_t;
typedef __attribute__((address_space(3))) void lds_void_t;

__device__ __forceinline__ void async16(const void* g, void* l) {
    // direct global->LDS, 16B per lane (dest = wave-uniform base + lane*16)
    __builtin_amdgcn_global_load_lds((glb_void_t*)(uintptr_t)g,
                                     (lds_void_t*)(uint32_t)(uintptr_t)l,
                                     16, 0, 0);
}

__device__ __forceinline__ unsigned short f32_to_bf16_rne(float f) {
    union { float f; uint32_t u; } v; v.f = f;
    uint32_t u = v.u;
    u += 0x7FFFu + ((u >> 16) & 1u);
    return (unsigned short)(u >> 16);
}

__device__ __forceinline__ unsigned short sign_to_bf16(float f) {
    union { float f; uint32_t u; } v; v.f = f;
    if ((v.u & 0x7FFFFFFFu) == 0u) return 0;                      // sign(0) = 0
    return (unsigned short)(0x3F80u | ((v.u >> 16) & 0x8000u));   // +-1.0 bf16
}

// ---- Phase 1: conversions (memory-bound, 16B loads / 16B stores) ----

__global__ void convert_x_kernel(const float* __restrict__ x,
                                 unsigned short* __restrict__ xb, int n8) {
    int stride = gridDim.x * blockDim.x;
    for (int i = blockIdx.x * blockDim.x + threadIdx.x; i < n8; i += stride) {
        const float4* p = (const float4*)x + (size_t)i * 2;
        float4 a = p[0], b = p[1];
        uint4 o;
        o.x = (uint32_t)f32_to_bf16_rne(a.x) | ((uint32_t)f32_to_bf16_rne(a.y) << 16);
        o.y = (uint32_t)f32_to_bf16_rne(a.z) | ((uint32_t)f32_to_bf16_rne(a.w) << 16);
        o.z = (uint32_t)f32_to_bf16_rne(b.x) | ((uint32_t)f32_to_bf16_rne(b.y) << 16);
        o.w = (uint32_t)f32_to_bf16_rne(b.z) | ((uint32_t)f32_to_bf16_rne(b.w) << 16);
        ((uint4*)xb)[i] = o;
    }
}

__global__ void convert_w_kernel(const float* __restrict__ w,
                                 unsigned short* __restrict__ wb, int n8) {
    int stride = gridDim.x * blockDim.x;
    for (int i = blockIdx.x * blockDim.x + threadIdx.x; i < n8; i += stride) {
        const float4* p = (const float4*)w + (size_t)i * 2;
        float4 a = p[0], b = p[1];
        uint4 o;
        o.x = (uint32_t)sign_to_bf16(a.x) | ((uint32_t)sign_to_bf16(a.y) << 16);
        o.y = (uint32_t)sign_to_bf16(a.z) | ((uint32_t)sign_to_bf16(a.w) << 16);
        o.z = (uint32_t)sign_to_bf16(b.x) | ((uint32_t)sign_to_bf16(b.y) << 16);
        o.w = (uint32_t)sign_to_bf16(b.z) | ((uint32_t)sign_to_bf16(b.w) << 16);
        ((uint4*)wb)[i] = o;
    }
}

// ---- Phase 2: 256x256-tile GEMM, 16x16x32 MFMA, 2-barrier K-tile ----
// C = Xb (M x K) * Wb^T (K x N) + bias; Xb row-major MxK, Wb row-major NxK.
// LDS: [2 buf][4 sect: A0,A1,B0,B1][128 rows x 64 cols bf16] = 128 KiB.
// XOR-swizzle T2 (16x16-read conflict-free): colbyte ^= (row&7)<<4.
// Round 6: NO explicit lgkmcnt(0)/sched_barrier in phases. ds_reads are
// typed compiler-visible loads; the compiler emits counted lgkmcnt(N)
// before each consuming MFMA (per-operand waits), letting reads overlap
// MFMA within and across phases. Hazard ledger still holds because every
// ds_read's consuming MFMA precedes the next barrier in program order:
//   BAR_a after the kk=1 MFMA block: all B-reads of buf consumed (hence
//     complete) -> staging B(t+2) into buf's B-sects is race-free.
//   BAR_b at tile end after vmcnt(4) (asm, "memory" clobber - typed loads
//     cannot cross it): A(t+1),B(t+1) staged data visible; A-sect WAR
//     closed (P3/P4 A-reads consumed by MFMAs before BAR_b).

#define BAR   __builtin_amdgcn_s_barrier()
#define VM4   asm volatile("s_waitcnt vmcnt(4)" ::: "memory")
#define VM0   asm volatile("s_waitcnt vmcnt(0)" ::: "memory")

#define RDA(BUFV, MLO, KK) \
    _Pragma("unroll") for (int mm = 0; mm < 4; ++mm) \
        a[mm] = rdfrag((BUFV), wm, ((MLO) + mm) * 16, (KK));

#define RDB(BUFV, KK) \
    _Pragma("unroll") for (int nn = 0; nn < 4; ++nn) \
        b[nn][(KK)] = rdfrag((BUFV), sectB, rB + nn * 16, (KK));

#define MM16R(MB, KK) \
    __builtin_amdgcn_s_setprio(1); \
    _Pragma("unroll") for (int mm = 0; mm < 4; ++mm) \
    _Pragma("unroll") for (int nn = 0; nn < 4; ++nn) \
        acc[(MB) + mm][nn] = __builtin_amdgcn_mfma_f32_16x16x32_bf16( \
            a[mm], b[nn][(KK)], acc[(MB) + mm][nn], 0, 0, 0); \
    __builtin_amdgcn_s_setprio(0);

// One K-tile t. P1/P2 stage A-halves of t+1 (other buffer);
// P3/P4 stage B-halves of t+2 (current buffer, protected by BAR_a).
#define KT(T, SA, SB, VMW) do { \
    const int buf_ = (T) & 1; const int nbuf_ = buf_ ^ 1; \
    if (SA) stage(nbuf_, 0, xb, brow, ((T) + 1) * 64); \
    RDA(buf_, 0, 0) RDB(buf_, 0) \
    MM16R(0, 0) \
    if (SA) stage(nbuf_, 1, xb, brow + 128, ((T) + 1) * 64); \
    RDA(buf_, 0, 1) RDB(buf_, 1) \
    MM16R(0, 1) \
    BAR;                             /* BAR_a: B-reads consumed -> B-stage safe */ \
    if (SB) stage(buf_, 2, wb, bcol, ((T) + 2) * 64); \
    RDA(buf_, 4, 0) \
    MM16R(4, 0) \
    if (SB) stage(buf_, 3, wb, bcol + 128, ((T) + 2) * 64); \
    RDA(buf_, 4, 1) \
    MM16R(4, 1) \
    VMW; \
    BAR;                             /* BAR_b: staged data + A-sect WAR */ \
} while (0)

__global__ __launch_bounds__(512, 2)
void gemm_bin_kernel(const unsigned short* __restrict__ xb,
                     const unsigned short* __restrict__ wb,
                     const float* __restrict__ bias,
                     float* __restrict__ out) {
    __shared__ __align__(16) unsigned short lds[2][4][8192];

    const int tid  = threadIdx.x;
    const int wid  = tid >> 6;
    const int lane = tid & 63;

    // XCD-aware swizzle: 512 blocks, 8 XCDs, 64 contiguous tiles per XCD
    const int bid  = blockIdx.x;
    const int swzb = (bid & 7) * 64 + (bid >> 3);
    const int brow = (swzb >> 4) * 256;      // 32 M-tiles
    const int bcol = (swzb & 15) * 256;      // 16 N-tiles

    const int wm = wid >> 2;                 // 0..1: A half (row block of 128)
    const int wn = wid & 3;                  // 0..3: 64-col block
    const int fr  = lane & 15;
    const int g16 = (lane >> 4) << 4;        // k-group byte offset (16x16 frag)
    const int sw  = (lane & 7) << 4;         // T2 swizzle XOR == (row&7)<<4
    const int sectB = 2 + (wn >> 1);
    const int rB    = (wn & 1) * 64;

    f32x4  acc[8][4] = {};
    bf16x8 a[4], b[4][2];

    // staging: half-tile 128x64 bf16, 16 chunks of 1KB; wave w -> chunks 2w,2w+1.
    // linear LDS dest; global source pre-swizzled: colE = ((lane&7)^(lane>>3))*8
    const int ssub  = lane >> 3;
    const int scolE = ((lane & 7) ^ ssub) * 8;
    auto stage = [&](int bufv, int sect, const unsigned short* g, int row0, int k0) {
        unsigned short* lb = &lds[bufv][sect][0];
        #pragma unroll
        for (int j = 0; j < 2; ++j) {
            const int c = wid * 2 + j;
            const int r = c * 8 + ssub;
            async16(g + (size_t)(row0 + r) * K_DIM + (k0 + scolE),
                    lb + c * 512 + lane * 8);
        }
    };

    // 16x16 frag read: row = rbase + (lane&15), kbyte = kk*64 + (lane>>4)*16
    auto rdfrag = [&](int bufv, int sect, int rbase, int kk) -> bf16x8 {
        const char* base = (const char*)&lds[bufv][sect][0];
        const int off = (rbase + fr) * 128 + (((kk * 64) + g16) ^ sw);
        return *(const bf16x8*)(base + off);
    };

    // prologue: K-tile 0 (A0,A1,B0,B1 -> buf0) + B-halves of K-tile 1 -> buf1
    stage(0, 0, xb, brow,        0);
    stage(0, 1, xb, brow + 128,  0);
    stage(0, 2, wb, bcol,        0);
    stage(0, 3, wb, bcol + 128,  0);
    stage(1, 2, wb, bcol,       64);
    stage(1, 3, wb, bcol + 128, 64);
    VM4;                 // K-tile 0 fully landed; B(1) halves may be in flight
    BAR;

    #pragma unroll 2
    for (int t = 0; t < NT - 2; ++t) KT(t, 1, 1, VM4);
    KT(NT - 2, 1, 0, VM0);           // stage A(63) only; drain before last tile
    KT(NT - 1, 0, 0, (void)0);       // pure compute

    // epilogue: C/D layout col = lane&15, row = (lane>>4)*4 + reg
    const int wrow = wm * 128, wcol = wn * 64;
    float bv[4];
    #pragma unroll
    for (int n = 0; n < 4; ++n) bv[n] = bias[bcol + wcol + n * 16 + fr];
    const int r4 = (lane >> 4) * 4;
    #pragma unroll
    for (int m = 0; m < 8; ++m) {
        #pragma unroll
        for (int rr = 0; rr < 4; ++rr) {
            const int row = brow + wrow + m * 16 + r4 + rr;
            float* orow = out + (size_t)row * N_DIM + bcol + wcol;
            #pragma unroll
            for (int n = 0; n < 4; ++n)
                orow[n * 16 + fr] = acc[m][n][rr] + bv[n];
        }
    }
}

// ---- Fallback if ws too small: naive fp32 (correct, slow; safety net) ----

__global__ void naive_kernel(const float* __restrict__ x,
                             const float* __restrict__ w,
                             const float* __restrict__ bias,
                             float* __restrict__ out) {
    const size_t total = (size_t)M_DIM * N_DIM;
    for (size_t idx = (size_t)blockIdx.x * blockDim.x + threadIdx.x; idx < total;
         idx += (size_t)gridDim.x * blockDim.x) {
        const size_t row = idx >> 12;
        const size_t col = idx & 4095;
        const float4* xr  = (const float4*)(x + row * K_DIM);
        const float4* wrp = (const float4*)(w + col * K_DIM);
        float s = 0.f;
        for (int k = 0; k < K_DIM / 4; ++k) {
            float4 a = xr[k], bq = wrp[k];
            s += a.x * (bq.x > 0.f ? 1.f : (bq.x < 0.f ? -1.f : 0.f));
            s += a.y * (bq.y > 0.f ? 1.f : (bq.y < 0.f ? -1.f : 0.f));
            s += a.z * (bq.z > 0.f ? 1.f : (bq.z < 0.f ? -1.f : 0.f));
            s += a.w * (bq.w > 0.f ? 1.f : (bq.w < 0.f ? -1.f : 0.f));
        }
        out[idx] = s + bias[col];
    }
}

extern "C" void kernel_launch(void* const* d_in, const int* in_sizes, int n_in,
                              void* d_out, int out_size, void* d_ws, size_t ws_size,
                              hipStream_t stream) {
    const float* x    = (const float*)d_in[0];
    const float* w    = (const float*)d_in[1];
    const float* bias = (const float*)d_in[2];
    float* out = (float*)d_out;

    const size_t xb_bytes = (size_t)M_DIM * K_DIM * 2;   // 64 MB
    const size_t wb_bytes = (size_t)N_DIM * K_DIM * 2;   // 32 MB

    if (ws_size >= xb_bytes + wb_bytes) {
        unsigned short* xb = (unsigned short*)d_ws;
        unsigned short* wb = (unsigned short*)((char*)d_ws + xb_bytes);
        convert_x_kernel<<<2048, 256, 0, stream>>>(x, xb, (int)((size_t)M_DIM * K_DIM / 8));
        convert_w_kernel<<<2048, 256, 0, stream>>>(w, wb, (int)((size_t)N_DIM * K_DIM / 8));
        gemm_bin_kernel<<<dim3((M_DIM / 256) * (N_DIM / 256)), dim3(512), 0, stream>>>(
            xb, wb, bias, out);
    } else {
        naive_kernel<<<4096, 256, 0, stream>>>(x, w, bias, out);
    }
}

// Round 7
// 193.239 us; speedup vs baseline: 1.3841x; 1.3564x over previous
//
#include <hip/hip_runtime.h>
#include <hip/hip_bf16.h>
#include <stdint.h>

#define M_DIM 8192
#define N_DIM 4096
#define K_DIM 4096

#define NT 64              // K-tiles of BK=64

using i32x4 = __attribute__((ext_vector_type(4))) int;

typedef const __attribute__((address_space(1))) void glb_void_t;
typedef __attribute__((address_space(3))) void lds_void_t;

__device__ __forceinline__ void async16(const void* g, void* l) {
    // direct global->LDS, 16B per lane (dest = wave-uniform base + lane*16)
    __builtin_amdgcn_global_load_lds((glb_void_t*)(uintptr_t)g,
                                     (lds_void_t*)(uint32_t)(uintptr_t)l,
                                     16, 0, 0);
}

__device__ __forceinline__ int sgn_i8(float f) {
    union { float f; uint32_t u; } v; v.f = f;
    if ((v.u & 0x7FFFFFFFu) == 0u) return 0;          // sign(0) = 0
    return (v.u >> 31) ? -1 : 1;
}

// ---- Phase 1a: W sign -> i8 {-1,0,+1}. 64MB read, 16MB write ----

__global__ void convert_w_kernel(const float* __restrict__ w,
                                 unsigned char* __restrict__ wq, int n4) {
    int stride = gridDim.x * blockDim.x;
    for (int i = blockIdx.x * blockDim.x + threadIdx.x; i < n4; i += stride) {
        float4 v = ((const float4*)w)[i];
        uint32_t o = ((uint32_t)(uint8_t)sgn_i8(v.x)) |
                     ((uint32_t)(uint8_t)sgn_i8(v.y) << 8) |
                     ((uint32_t)(uint8_t)sgn_i8(v.z) << 16) |
                     ((uint32_t)(uint8_t)sgn_i8(v.w) << 24);
        ((uint32_t*)wq)[i] = o;
    }
}

// ---- Phase 1b: X per-row i8 quant (fused max + quantize, single pass) ----
// One block per row. scale = rowmax/127, q = rne(x*127/rowmax). i32 accum in
// the GEMM is exact, so quant error is the only error source.

__global__ __launch_bounds__(256)
void convert_x_kernel(const float* __restrict__ x,
                      unsigned char* __restrict__ xq,
                      float* __restrict__ scales) {
    const int row = blockIdx.x;
    const int tid = threadIdx.x;
    const float4* xr = (const float4*)(x + (size_t)row * K_DIM);
    float4 v[4];
    float m = 0.f;
    #pragma unroll
    for (int j = 0; j < 4; ++j) {
        v[j] = xr[j * 256 + tid];
        m = fmaxf(m, fmaxf(fmaxf(fabsf(v[j].x), fabsf(v[j].y)),
                           fmaxf(fabsf(v[j].z), fabsf(v[j].w))));
    }
    #pragma unroll
    for (int off = 32; off >= 1; off >>= 1)
        m = fmaxf(m, __shfl_xor(m, off));
    __shared__ float wmax[4];
    if ((tid & 63) == 0) wmax[tid >> 6] = m;
    __syncthreads();
    m = fmaxf(fmaxf(wmax[0], wmax[1]), fmaxf(wmax[2], wmax[3]));
    const float inv = (m > 0.f) ? 127.0f / m : 0.f;
    if (tid == 0) scales[row] = (m > 0.f) ? m / 127.0f : 0.f;
    uint32_t* oq = (uint32_t*)(xq + (size_t)row * K_DIM);
    #pragma unroll
    for (int j = 0; j < 4; ++j) {
        float q0 = fminf(fmaxf(rintf(v[j].x * inv), -127.f), 127.f);
        float q1 = fminf(fmaxf(rintf(v[j].y * inv), -127.f), 127.f);
        float q2 = fminf(fmaxf(rintf(v[j].z * inv), -127.f), 127.f);
        float q3 = fminf(fmaxf(rintf(v[j].w * inv), -127.f), 127.f);
        uint32_t o = ((uint32_t)(uint8_t)(int)q0) |
                     ((uint32_t)(uint8_t)(int)q1 << 8) |
                     ((uint32_t)(uint8_t)(int)q2 << 16) |
                     ((uint32_t)(uint8_t)(int)q3 << 24);
        oq[j * 256 + tid] = o;
    }
}

// ---- Phase 2: 256x256-tile i8 GEMM, mfma_i32_16x16x64_i8, 2-barrier K-tile ----
// C = Xq (M x K, i8) * Wq^T (K x N, i8) -> i32 exact; y = scale[row]*acc + bias.
// LDS: [2 buf][4 sect: A0,A1,B0,B1][128 rows x 64 cols i8] = 64 KiB -> 2 blk/CU.
// No swizzle needed: 64B row stride makes the 16x16 frag read naturally
// conflict-free (slot = (row&1)*4 + (lane>>4): 8 lanes/slot uniform), and
// staging is a single linear 16B/thread global_load_lds (512 thr = 8KB sect).
// Sync ledger (2 barriers/K-tile):
//   BAR_a after all 32 MFMAs: every wave's A+B reads of buf consumed/retired
//     -> staging B(t+2) into buf's B-sects race-free.
//   BAR_b after vmcnt(2): queue = [B(t+1)x2, A(t+1)x2, B(t+2)x2]; keeping 2
//     leaves only B(t+2) in flight -> tile t+1 data visible to all waves.
//   A-stage (into nbuf) WAR closed by BAR_b(t-1) (reads retired pre-MFMA).

#define BAR   __builtin_amdgcn_s_barrier()
#define VM2   asm volatile("s_waitcnt vmcnt(2)" ::: "memory")
#define VM0   asm volatile("s_waitcnt vmcnt(0)" ::: "memory")

#define RDA(BUFV, MLO) \
    _Pragma("unroll") for (int mm = 0; mm < 4; ++mm) \
        a[mm] = rdfrag((BUFV), wm, ((MLO) + mm) * 16);

#define RDB(BUFV) \
    _Pragma("unroll") for (int nn = 0; nn < 4; ++nn) \
        b[nn] = rdfrag((BUFV), sectB, rB + nn * 16);

#define MM16(MB) \
    __builtin_amdgcn_s_setprio(1); \
    _Pragma("unroll") for (int mm = 0; mm < 4; ++mm) \
    _Pragma("unroll") for (int nn = 0; nn < 4; ++nn) \
        acc[(MB) + mm][nn] = __builtin_amdgcn_mfma_i32_16x16x64_i8( \
            a[mm], b[nn], acc[(MB) + mm][nn], 0, 0, 0); \
    __builtin_amdgcn_s_setprio(0);

// One K-tile t. A-halves of t+1 staged into nbuf early; B-halves of t+2
// staged into buf after BAR_a.
#define KT(T, SA, SB, VMW) do { \
    const int buf_ = (T) & 1; const int nbuf_ = buf_ ^ 1; \
    if (SA) stage(nbuf_, 0, xq, brow, ((T) + 1) * 64); \
    RDB(buf_) RDA(buf_, 0) \
    MM16(0) \
    if (SA) stage(nbuf_, 1, xq, brow + 128, ((T) + 1) * 64); \
    RDA(buf_, 4) \
    MM16(4) \
    BAR;                             /* BAR_a: all buf reads consumed */ \
    if (SB) stage(buf_, 2, wq, bcol, ((T) + 2) * 64); \
    if (SB) stage(buf_, 3, wq, bcol + 128, ((T) + 2) * 64); \
    VMW; \
    BAR;                             /* BAR_b: tile t+1 staged data visible */ \
} while (0)

__global__ __launch_bounds__(512, 2)
void gemm_bin_kernel(const unsigned char* __restrict__ xq,
                     const unsigned char* __restrict__ wq,
                     const float* __restrict__ scales,
                     const float* __restrict__ bias,
                     float* __restrict__ out) {
    __shared__ __align__(16) unsigned char lds[2][4][8192];

    const int tid  = threadIdx.x;
    const int wid  = tid >> 6;
    const int lane = tid & 63;

    // XCD-aware swizzle: 512 blocks, 8 XCDs, 64 contiguous tiles per XCD
    const int bid  = blockIdx.x;
    const int swzb = (bid & 7) * 64 + (bid >> 3);
    const int brow = (swzb >> 4) * 256;      // 32 M-tiles
    const int bcol = (swzb & 15) * 256;      // 16 N-tiles

    const int wm = wid >> 2;                 // 0..1: A half (row block of 128)
    const int wn = wid & 3;                  // 0..3: 64-col block
    const int fr  = lane & 15;
    const int g16 = (lane >> 4) << 4;        // k-group byte offset (16B chunk)
    const int sectB = 2 + (wn >> 1);
    const int rB    = (wn & 1) * 64;

    i32x4 acc[8][4] = {};
    i32x4 a[4], b[4];

    // staging: half-tile 128x64 i8 = 8KB = 512 threads x 16B, fully linear.
    auto stage = [&](int bufv, int sect, const unsigned char* g, int row0, int k0) {
        async16(g + (size_t)(row0 + (tid >> 2)) * K_DIM + (k0 + (tid & 3) * 16),
                &lds[bufv][sect][0] + tid * 16);
    };

    // 16x16x64 i8 frag: row = rbase + (lane&15), bytes (lane>>4)*16 .. +15
    auto rdfrag = [&](int bufv, int sect, int rbase) -> i32x4 {
        const unsigned char* base = &lds[bufv][sect][0];
        return *(const i32x4*)(base + (rbase + fr) * 64 + g16);
    };

    // prologue: K-tile 0 (A0,A1,B0,B1 -> buf0) + B-halves of K-tile 1 -> buf1
    stage(0, 0, xq, brow,        0);
    stage(0, 1, xq, brow + 128,  0);
    stage(0, 2, wq, bcol,        0);
    stage(0, 3, wq, bcol + 128,  0);
    stage(1, 2, wq, bcol,       64);
    stage(1, 3, wq, bcol + 128, 64);
    VM2;                 // K-tile 0 fully landed; B(1) halves may be in flight
    BAR;

    #pragma unroll 2
    for (int t = 0; t < NT - 2; ++t) KT(t, 1, 1, VM2);
    KT(NT - 2, 1, 0, VM0);           // stage A(63) only; drain before last tile
    KT(NT - 1, 0, 0, (void)0);       // pure compute

    // epilogue: C/D layout col = lane&15, row = (lane>>4)*4 + reg (shape-det.)
    const int wrow = wm * 128, wcol = wn * 64;
    float bv[4];
    #pragma unroll
    for (int n = 0; n < 4; ++n) bv[n] = bias[bcol + wcol + n * 16 + fr];
    const int r4 = (lane >> 4) * 4;
    #pragma unroll
    for (int m = 0; m < 8; ++m) {
        #pragma unroll
        for (int rr = 0; rr < 4; ++rr) {
            const int row = brow + wrow + m * 16 + r4 + rr;
            const float sc = scales[row];
            float* orow = out + (size_t)row * N_DIM + bcol + wcol;
            #pragma unroll
            for (int n = 0; n < 4; ++n)
                orow[n * 16 + fr] = (float)acc[m][n][rr] * sc + bv[n];
        }
    }
}

// ---- Fallback if ws too small: naive fp32 (correct, slow; safety net) ----

__global__ void naive_kernel(const float* __restrict__ x,
                             const float* __restrict__ w,
                             const float* __restrict__ bias,
                             float* __restrict__ out) {
    const size_t total = (size_t)M_DIM * N_DIM;
    for (size_t idx = (size_t)blockIdx.x * blockDim.x + threadIdx.x; idx < total;
         idx += (size_t)gridDim.x * blockDim.x) {
        const size_t row = idx >> 12;
        const size_t col = idx & 4095;
        const float4* xr  = (const float4*)(x + row * K_DIM);
        const float4* wrp = (const float4*)(w + col * K_DIM);
        float s = 0.f;
        for (int k = 0; k < K_DIM / 4; ++k) {
            float4 a = xr[k], bq = wrp[k];
            s += a.x * (bq.x > 0.f ? 1.f : (bq.x < 0.f ? -1.f : 0.f));
            s += a.y * (bq.y > 0.f ? 1.f : (bq.y < 0.f ? -1.f : 0.f));
            s += a.z * (bq.z > 0.f ? 1.f : (bq.z < 0.f ? -1.f : 0.f));
            s += a.w * (bq.w > 0.f ? 1.f : (bq.w < 0.f ? -1.f : 0.f));
        }
        out[idx] = s + bias[col];
    }
}

extern "C" void kernel_launch(void* const* d_in, const int* in_sizes, int n_in,
                              void* d_out, int out_size, void* d_ws, size_t ws_size,
                              hipStream_t stream) {
    const float* x    = (const float*)d_in[0];
    const float* w    = (const float*)d_in[1];
    const float* bias = (const float*)d_in[2];
    float* out = (float*)d_out;

    const size_t xq_bytes = (size_t)M_DIM * K_DIM;       // 32 MB
    const size_t wq_bytes = (size_t)N_DIM * K_DIM;       // 16 MB
    const size_t sc_bytes = (size_t)M_DIM * sizeof(float);

    if (ws_size >= xq_bytes + wq_bytes + sc_bytes) {
        unsigned char* xq = (unsigned char*)d_ws;
        unsigned char* wq = (unsigned char*)d_ws + xq_bytes;
        float* scales     = (float*)((char*)d_ws + xq_bytes + wq_bytes);
        convert_w_kernel<<<2048, 256, 0, stream>>>(w, wq,
            (int)((size_t)N_DIM * K_DIM / 4));
        convert_x_kernel<<<M_DIM, 256, 0, stream>>>(x, xq, scales);
        gemm_bin_kernel<<<dim3((M_DIM / 256) * (N_DIM / 256)), dim3(512), 0, stream>>>(
            xq, wq, scales, bias, out);
    } else {
        naive_kernel<<<4096, 256, 0, stream>>>(x, w, bias, out);
    }
}

// Round 8
// 189.463 us; speedup vs baseline: 1.4117x; 1.0199x over previous
//
#include <hip/hip_runtime.h>
#include <hip/hip_bf16.h>
#include <stdint.h>

#define M_DIM 8192
#define N_DIM 4096
#define K_DIM 4096

#define NT 64              // K-tiles of BK=64

using i32x4 = __attribute__((ext_vector_type(4))) int;

typedef const __attribute__((address_space(1))) void glb_void_t;
typedef __attribute__((address_space(3))) void lds_void_t;

__device__ __forceinline__ void async16(const void* g, void* l) {
    // direct global->LDS, 16B per lane (dest = wave-uniform base + lane*16)
    __builtin_amdgcn_global_load_lds((glb_void_t*)(uintptr_t)g,
                                     (lds_void_t*)(uint32_t)(uintptr_t)l,
                                     16, 0, 0);
}

__device__ __forceinline__ int sgn_i8(float f) {
    union { float f; uint32_t u; } v; v.f = f;
    if ((v.u & 0x7FFFFFFFu) == 0u) return 0;          // sign(0) = 0
    return (v.u >> 31) ? -1 : 1;
}

// ---- Phase 1a: W sign -> i8 {-1,0,+1}. 64MB read, 16MB write ----

__global__ void convert_w_kernel(const float* __restrict__ w,
                                 unsigned char* __restrict__ wq, int n4) {
    int stride = gridDim.x * blockDim.x;
    for (int i = blockIdx.x * blockDim.x + threadIdx.x; i < n4; i += stride) {
        float4 v = ((const float4*)w)[i];
        uint32_t o = ((uint32_t)(uint8_t)sgn_i8(v.x)) |
                     ((uint32_t)(uint8_t)sgn_i8(v.y) << 8) |
                     ((uint32_t)(uint8_t)sgn_i8(v.z) << 16) |
                     ((uint32_t)(uint8_t)sgn_i8(v.w) << 24);
        ((uint32_t*)wq)[i] = o;
    }
}

// ---- Phase 1b: X per-row i8 quant (fused max + quantize, single pass) ----
// One block per row. scale = rowmax/127, q = rne(x*127/rowmax). i32 accum in
// the GEMM is exact, so quant error is the only error source.

__global__ __launch_bounds__(256)
void convert_x_kernel(const float* __restrict__ x,
                      unsigned char* __restrict__ xq,
                      float* __restrict__ scales) {
    const int row = blockIdx.x;
    const int tid = threadIdx.x;
    const float4* xr = (const float4*)(x + (size_t)row * K_DIM);
    float4 v[4];
    float m = 0.f;
    #pragma unroll
    for (int j = 0; j < 4; ++j) {
        v[j] = xr[j * 256 + tid];
        m = fmaxf(m, fmaxf(fmaxf(fabsf(v[j].x), fabsf(v[j].y)),
                           fmaxf(fabsf(v[j].z), fabsf(v[j].w))));
    }
    #pragma unroll
    for (int off = 32; off >= 1; off >>= 1)
        m = fmaxf(m, __shfl_xor(m, off));
    __shared__ float wmax[4];
    if ((tid & 63) == 0) wmax[tid >> 6] = m;
    __syncthreads();
    m = fmaxf(fmaxf(wmax[0], wmax[1]), fmaxf(wmax[2], wmax[3]));
    const float inv = (m > 0.f) ? 127.0f / m : 0.f;
    if (tid == 0) scales[row] = (m > 0.f) ? m / 127.0f : 0.f;
    uint32_t* oq = (uint32_t*)(xq + (size_t)row * K_DIM);
    #pragma unroll
    for (int j = 0; j < 4; ++j) {
        float q0 = fminf(fmaxf(rintf(v[j].x * inv), -127.f), 127.f);
        float q1 = fminf(fmaxf(rintf(v[j].y * inv), -127.f), 127.f);
        float q2 = fminf(fmaxf(rintf(v[j].z * inv), -127.f), 127.f);
        float q3 = fminf(fmaxf(rintf(v[j].w * inv), -127.f), 127.f);
        uint32_t o = ((uint32_t)(uint8_t)(int)q0) |
                     ((uint32_t)(uint8_t)(int)q1 << 8) |
                     ((uint32_t)(uint8_t)(int)q2 << 16) |
                     ((uint32_t)(uint8_t)(int)q3 << 24);
        oq[j * 256 + tid] = o;
    }
}

// ---- Phase 2: 256x256-tile i8 GEMM, mfma_i32_16x16x64_i8, 2-barrier K-tile ----
// C = Xq (M x K, i8) * Wq^T (K x N, i8) -> i32 exact; y = scale[row]*acc + bias.
// LDS: [2 buf][4 sect: A0,A1,B0,B1][128 rows x 64 cols i8] = 64 KiB -> 2 blk/CU.
// T2 swizzle for 64B-row geometry (round 8): logical (row, chunk16) stored at
// chunk ^ ((row>>1)&3). Rationale: bank-group = bits[6:4] = {row&1, chunk};
// unswizzled frag reads have constant chunk per 16-lane quarter -> each 8-lane
// phase hits 2/8 groups 4-way (measured +4 cyc/read, 1.26e7 conflicts).
// Swizzled: each 8-lane phase covers all 8 groups exactly once.
// Both-sides-or-neither: linear global_load_lds dest + inverse-swizzled global
// source (chunk_src = (tid&3) ^ ((tid>>3)&3), involution) + swizzled read.
// Sync ledger (2 barriers/K-tile):
//   BAR_a after all 32 MFMAs: every wave's A+B reads of buf consumed/retired
//     -> staging B(t+2) into buf's B-sects race-free.
//   BAR_b after vmcnt(2): queue = [B(t+1)x2, A(t+1)x2, B(t+2)x2]; keeping 2
//     leaves only B(t+2) in flight -> tile t+1 data visible to all waves.
//   A-stage (into nbuf) WAR closed by BAR_b(t-1) (reads retired pre-MFMA).

#define BAR   __builtin_amdgcn_s_barrier()
#define VM2   asm volatile("s_waitcnt vmcnt(2)" ::: "memory")
#define VM0   asm volatile("s_waitcnt vmcnt(0)" ::: "memory")

#define RDA(BUFV, MLO) \
    _Pragma("unroll") for (int mm = 0; mm < 4; ++mm) \
        a[mm] = rdfrag((BUFV), wm, ((MLO) + mm) * 16);

#define RDB(BUFV) \
    _Pragma("unroll") for (int nn = 0; nn < 4; ++nn) \
        b[nn] = rdfrag((BUFV), sectB, rB + nn * 16);

#define MM16(MB) \
    __builtin_amdgcn_s_setprio(1); \
    _Pragma("unroll") for (int mm = 0; mm < 4; ++mm) \
    _Pragma("unroll") for (int nn = 0; nn < 4; ++nn) \
        acc[(MB) + mm][nn] = __builtin_amdgcn_mfma_i32_16x16x64_i8( \
            a[mm], b[nn], acc[(MB) + mm][nn], 0, 0, 0); \
    __builtin_amdgcn_s_setprio(0);

// One K-tile t. A-halves of t+1 staged into nbuf early; B-halves of t+2
// staged into buf after BAR_a.
#define KT(T, SA, SB, VMW) do { \
    const int buf_ = (T) & 1; const int nbuf_ = buf_ ^ 1; \
    if (SA) stage(nbuf_, 0, xq, brow, ((T) + 1) * 64); \
    RDB(buf_) RDA(buf_, 0) \
    MM16(0) \
    if (SA) stage(nbuf_, 1, xq, brow + 128, ((T) + 1) * 64); \
    RDA(buf_, 4) \
    MM16(4) \
    BAR;                             /* BAR_a: all buf reads consumed */ \
    if (SB) stage(buf_, 2, wq, bcol, ((T) + 2) * 64); \
    if (SB) stage(buf_, 3, wq, bcol + 128, ((T) + 2) * 64); \
    VMW; \
    BAR;                             /* BAR_b: tile t+1 staged data visible */ \
} while (0)

__global__ __launch_bounds__(512, 2)
void gemm_bin_kernel(const unsigned char* __restrict__ xq,
                     const unsigned char* __restrict__ wq,
                     const float* __restrict__ scales,
                     const float* __restrict__ bias,
                     float* __restrict__ out) {
    __shared__ __align__(16) unsigned char lds[2][4][8192];

    const int tid  = threadIdx.x;
    const int wid  = tid >> 6;
    const int lane = tid & 63;

    // XCD-aware swizzle: 512 blocks, 8 XCDs, 64 contiguous tiles per XCD
    const int bid  = blockIdx.x;
    const int swzb = (bid & 7) * 64 + (bid >> 3);
    const int brow = (swzb >> 4) * 256;      // 32 M-tiles
    const int bcol = (swzb & 15) * 256;      // 16 N-tiles

    const int wm = wid >> 2;                 // 0..1: A half (row block of 128)
    const int wn = wid & 3;                  // 0..3: 64-col block
    const int fr  = lane & 15;
    const int g16 = (lane >> 4) << 4;        // logical k-chunk byte offset
    const int sw  = ((lane >> 1) & 3) << 4;  // T2: ((row>>1)&3)<<4, row=fr+16m
    const int sectB = 2 + (wn >> 1);
    const int rB    = (wn & 1) * 64;

    i32x4 acc[8][4] = {};
    i32x4 a[4], b[4];

    // staging: half-tile 128x64 i8 = 8KB = 512 threads x 16B, linear LDS dest;
    // global source chunk pre-swizzled (involution): (tid&3) ^ ((tid>>3)&3).
    const int srow = tid >> 2;
    const int scol = ((tid & 3) ^ ((tid >> 3) & 3)) * 16;
    auto stage = [&](int bufv, int sect, const unsigned char* g, int row0, int k0) {
        async16(g + (size_t)(row0 + srow) * K_DIM + (k0 + scol),
                &lds[bufv][sect][0] + tid * 16);
    };

    // 16x16x64 i8 frag: row = rbase + fr, logical chunk = lane>>4,
    // physical chunk = logical ^ ((row>>1)&3)  (sw precomputed)
    auto rdfrag = [&](int bufv, int sect, int rbase) -> i32x4 {
        const unsigned char* base = &lds[bufv][sect][0];
        return *(const i32x4*)(base + (rbase + fr) * 64 + (g16 ^ sw));
    };

    // prologue: K-tile 0 (A0,A1,B0,B1 -> buf0) + B-halves of K-tile 1 -> buf1
    stage(0, 0, xq, brow,        0);
    stage(0, 1, xq, brow + 128,  0);
    stage(0, 2, wq, bcol,        0);
    stage(0, 3, wq, bcol + 128,  0);
    stage(1, 2, wq, bcol,       64);
    stage(1, 3, wq, bcol + 128, 64);
    VM2;                 // K-tile 0 fully landed; B(1) halves may be in flight
    BAR;

    #pragma unroll 2
    for (int t = 0; t < NT - 2; ++t) KT(t, 1, 1, VM2);
    KT(NT - 2, 1, 0, VM0);           // stage A(63) only; drain before last tile
    KT(NT - 1, 0, 0, (void)0);       // pure compute

    // epilogue: C/D layout col = lane&15, row = (lane>>4)*4 + reg (shape-det.)
    const int wrow = wm * 128, wcol = wn * 64;
    float bv[4];
    #pragma unroll
    for (int n = 0; n < 4; ++n) bv[n] = bias[bcol + wcol + n * 16 + fr];
    const int r4 = (lane >> 4) * 4;
    #pragma unroll
    for (int m = 0; m < 8; ++m) {
        #pragma unroll
        for (int rr = 0; rr < 4; ++rr) {
            const int row = brow + wrow + m * 16 + r4 + rr;
            const float sc = scales[row];
            float* orow = out + (size_t)row * N_DIM + bcol + wcol;
            #pragma unroll
            for (int n = 0; n < 4; ++n)
                orow[n * 16 + fr] = (float)acc[m][n][rr] * sc + bv[n];
        }
    }
}

// ---- Fallback if ws too small: naive fp32 (correct, slow; safety net) ----

__global__ void naive_kernel(const float* __restrict__ x,
                             const float* __restrict__ w,
                             const float* __restrict__ bias,
                             float* __restrict__ out) {
    const size_t total = (size_t)M_DIM * N_DIM;
    for (size_t idx = (size_t)blockIdx.x * blockDim.x + threadIdx.x; idx < total;
         idx += (size_t)gridDim.x * blockDim.x) {
        const size_t row = idx >> 12;
        const size_t col = idx & 4095;
        const float4* xr  = (const float4*)(x + row * K_DIM);
        const float4* wrp = (const float4*)(w + col * K_DIM);
        float s = 0.f;
        for (int k = 0; k < K_DIM / 4; ++k) {
            float4 a = xr[k], bq = wrp[k];
            s += a.x * (bq.x > 0.f ? 1.f : (bq.x < 0.f ? -1.f : 0.f));
            s += a.y * (bq.y > 0.f ? 1.f : (bq.y < 0.f ? -1.f : 0.f));
            s += a.z * (bq.z > 0.f ? 1.f : (bq.z < 0.f ? -1.f : 0.f));
            s += a.w * (bq.w > 0.f ? 1.f : (bq.w < 0.f ? -1.f : 0.f));
        }
        out[idx] = s + bias[col];
    }
}

extern "C" void kernel_launch(void* const* d_in, const int* in_sizes, int n_in,
                              void* d_out, int out_size, void* d_ws, size_t ws_size,
                              hipStream_t stream) {
    const float* x    = (const float*)d_in[0];
    const float* w    = (const float*)d_in[1];
    const float* bias = (const float*)d_in[2];
    float* out = (float*)d_out;

    const size_t xq_bytes = (size_t)M_DIM * K_DIM;       // 32 MB
    const size_t wq_bytes = (size_t)N_DIM * K_DIM;       // 16 MB
    const size_t sc_bytes = (size_t)M_DIM * sizeof(float);

    if (ws_size >= xq_bytes + wq_bytes + sc_bytes) {
        unsigned char* xq = (unsigned char*)d_ws;
        unsigned char* wq = (unsigned char*)d_ws + xq_bytes;
        float* scales     = (float*)((char*)d_ws + xq_bytes + wq_bytes);
        convert_w_kernel<<<2048, 256, 0, stream>>>(w, wq,
            (int)((size_t)N_DIM * K_DIM / 4));
        convert_x_kernel<<<M_DIM, 256, 0, stream>>>(x, xq, scales);
        gemm_bin_kernel<<<dim3((M_DIM / 256) * (N_DIM / 256)), dim3(512), 0, stream>>>(
            xq, wq, scales, bias, out);
    } else {
        naive_kernel<<<4096, 256, 0, stream>>>(x, w, bias, out);
    }
}